// Round 2
// baseline (134842.932 us; speedup 1.0000x reference)
//
#include <hip/hip_runtime.h>
#include <hip/hip_bf16.h>

// Problem constants
#define BB   128   // batch
#define TT   400   // encoder length
#define KVD  128   // key/value dim (= layer2 hidden)
#define VV   1024  // vocab
#define EE   256   // embed dim
#define HH   512   // layer1 hidden
#define LL   300   // decode length
#define D1   896   // E + KV + H (layer1 input incl. recurrent)
#define NBLK 256
#define NTHR 256   // init kernel block size
#define DTHR 1024  // decoder block size: 16 waves = 4/SIMD -> TLP to hide remote-L2/L3 latency

// workspace layout (float units)
#define XT_SZ   (D1 * BB)             // 114688 floats per parity buffer
#define XT_OFF  0                     // 2 buffers
#define H2_SZ   (KVD * BB)            // 16384 floats per parity buffer
#define H2_OFF  (2 * XT_SZ)           // 229376
#define FLAG_OFF (H2_OFF + 2 * H2_SZ) // unsigned flags[256] + gen + isf
#define PLOT_OFF (BB * LL * VV)       // 39321600 (attn_plot offset in out)

typedef unsigned short ushort_t;

__device__ __forceinline__ float bf2f(ushort_t u) {
  return __uint_as_float(((unsigned)u) << 16);
}
__device__ __forceinline__ ushort_t f2bf(float f) {
  unsigned u = __float_as_uint(f);
  return (ushort_t)((u + 0x7FFFu + ((u >> 16) & 1u)) >> 16);  // RNE
}
__device__ __forceinline__ float sigm(float x) { return 1.0f / (1.0f + expf(-x)); }

// dtype-agnostic element load/store (isf: buffer is fp32, else bf16)
__device__ __forceinline__ float ldx(const void* p, size_t i, bool isf) {
  return isf ? ((const float*)p)[i] : bf2f(((const ushort_t*)p)[i]);
}
__device__ __forceinline__ void stx(void* p, size_t i, float v, bool isf) {
  if (isf) ((float*)p)[i] = v; else ((ushort_t*)p)[i] = f2bf(v);
}

// ---------------------------------------------------------------------------
// probe: decide whether float tensors are fp32 or bf16.
// ---------------------------------------------------------------------------
__global__ void probe_kernel(const void* __restrict__ w_out, float* __restrict__ ws) {
  if (blockIdx.x == 0 && threadIdx.x == 0) {
    const ushort_t* p = (const ushort_t*)w_out;
    int bad = 0;
    for (int i = 0; i < 512; ++i) {
      float v = bf2f(p[i]);
      if (!(fabsf(v) < 0.5f)) bad++;   // counts NaN/inf too
    }
    unsigned* flags = (unsigned*)(ws + FLAG_OFF);
    flags[NBLK + 1] = (bad > 0) ? 1u : 0u;
  }
}

// ---------------------------------------------------------------------------
// init: zero parity-0 state, seed <sos> embedding, zero barrier flags
// ---------------------------------------------------------------------------
__global__ void __launch_bounds__(NTHR) init_kernel(const void* __restrict__ emb,
                                                    float* __restrict__ ws) {
  unsigned* flags = (unsigned*)(ws + FLAG_OFF);
  const bool isf = flags[NBLK + 1] != 0;
  int idx = blockIdx.x * NTHR + threadIdx.x;
  if (idx < XT_SZ) {
    int k = idx >> 7;  // row of xT (col = idx & 127)
    ws[XT_OFF + idx] = (k < EE) ? ldx(emb, EE + k, isf) : 0.0f;  // SOS token = 1
  }
  int j = idx - XT_SZ;
  if (j >= 0 && j < H2_SZ) ws[H2_OFF + j] = 0.0f;
  int f = idx - (XT_SZ + H2_SZ);
  if (f >= 0 && f < NBLK + 1) flags[f] = 0u;   // flags[257] (isf) preserved
}

// ---------------------------------------------------------------------------
// grid barrier: per-block release flag, block 0 polls all, bumps generation
// ---------------------------------------------------------------------------
__device__ __forceinline__ void grid_barrier(unsigned* flags, unsigned* gen, unsigned target) {
  __threadfence();
  __syncthreads();
  const int tid = threadIdx.x;
  if (blockIdx.x == 0) {
    if (tid > 0 && tid < NBLK) {
      long spin = 0;
      while (__hip_atomic_load(&flags[tid], __ATOMIC_RELAXED, __HIP_MEMORY_SCOPE_AGENT) < target) {
        __builtin_amdgcn_s_sleep(2);
        if (++spin > (1L << 24)) break;
      }
    }
    __syncthreads();
    if (tid == 0)
      __hip_atomic_store(gen, target, __ATOMIC_RELEASE, __HIP_MEMORY_SCOPE_AGENT);
  } else {
    if (tid == 0) {
      __hip_atomic_store(&flags[blockIdx.x], target, __ATOMIC_RELEASE, __HIP_MEMORY_SCOPE_AGENT);
      long spin = 0;
      while (__hip_atomic_load(gen, __ATOMIC_RELAXED, __HIP_MEMORY_SCOPE_AGENT) < target) {
        __builtin_amdgcn_s_sleep(2);
        if (++spin > (1L << 24)) break;
      }
    }
    __syncthreads();
  }
  __threadfence();
}

// ---------------------------------------------------------------------------
// persistent decoder — 1024 threads/block (z = tid>>7 selects K-segment/row)
// ---------------------------------------------------------------------------
__global__ void __launch_bounds__(DTHR) decoder_kernel(
    const void* __restrict__ enc_key,
    const void* __restrict__ enc_value,
    const int*  __restrict__ enc_len,
    const int*  __restrict__ y,
    const void* __restrict__ emb,
    const void* __restrict__ w_ih1, const void* __restrict__ w_hh1,
    const void* __restrict__ b_ih1, const void* __restrict__ b_hh1,
    const void* __restrict__ w_ih2, const void* __restrict__ w_hh2,
    const void* __restrict__ b_ih2, const void* __restrict__ b_hh2,
    const void* __restrict__ w_out, const void* __restrict__ b_out,
    void* __restrict__ out, float* __restrict__ ws)
{
  __shared__ float sW1[8][D1];      // block w owns hu=2w,2w+1: rows 4h+g  (28.7 KB)
  __shared__ float sW2[4][640];     // blocks<128 own layer2 hidden w      (10.2 KB)
  __shared__ float sWo[4][256];     // block w owns vocab rows 4w..4w+3    (4 KB)
  __shared__ float sB1[8];
  __shared__ float sB2[4];
  __shared__ float sBo[4];
  __shared__ float sRed[16];
  __shared__ float sAttn[TT];
  __shared__ float sH2[KVD];
  __shared__ float sPA[8][4][BB];   // GEMM1 K-split partials (16 KB)
  __shared__ float sPO[8][BB];      // out-GEMM / GEMM2 / context partials (4 KB)

  const int tid = threadIdx.x;
  const int w   = blockIdx.x;
  unsigned* flags = (unsigned*)(ws + FLAG_OFF);
  unsigned* gen   = flags + NBLK;
  const bool isf  = flags[NBLK + 1] != 0;

  // ---- one-time LDS weight staging (-> fp32) ----
  for (int i = tid; i < 8 * D1; i += DTHR) {
    int r = i / D1, k = i - r * D1;        // r = 4h+g
    int g = r & 3, h = r >> 2;
    int R = g * HH + 2 * w + h;            // global gate row in [0,2048)
    sW1[r][k] = (k < EE + KVD) ? ldx(w_ih1, (size_t)R * (EE + KVD) + k, isf)
                               : ldx(w_hh1, (size_t)R * HH + (k - (EE + KVD)), isf);
  }
  if (tid < 8) {
    int R = (tid & 3) * HH + 2 * w + (tid >> 2);
    sB1[tid] = ldx(b_ih1, R, isf) + ldx(b_hh1, R, isf);
  }
  if (w < BB) {
    for (int i = tid; i < 4 * 640; i += DTHR) {
      int g = i / 640, k = i - g * 640;
      int R = g * KVD + w;                 // global gate row in [0,512)
      sW2[g][k] = (k < HH) ? ldx(w_ih2, (size_t)R * HH + k, isf)
                           : ldx(w_hh2, (size_t)R * KVD + (k - HH), isf);
    }
    if (tid < 4) {
      int R = tid * KVD + w;
      sB2[tid] = ldx(b_ih2, R, isf) + ldx(b_hh2, R, isf);
    }
  }
  for (int i = tid; i < 4 * 256; i += DTHR) {
    int r = i >> 8, d = i & 255;
    sWo[r][d] = ldx(w_out, (size_t)(4 * w + r) * 256 + d, isf);
  }
  if (tid < 4) sBo[tid] = ldx(b_out, 4 * w + tid, isf);
  __syncthreads();

  const int b = tid & 127;    // batch column
  const int z = tid >> 7;     // 0..7: K-segment / row selector
  float c1 = 0.0f;            // live in threads z<2: c1[hu=2w+z][b]
  float c2 = 0.0f;            // live in threads z==0 (w<128): c2[w][b]

  unsigned target = 0;

  for (int t = 0; t <= LL; ++t) {
    const int p0 = t & 1;
    float* xT0  = ws + XT_OFF + p0 * XT_SZ;
    float* xT1  = ws + XT_OFF + (p0 ^ 1) * XT_SZ;
    float* h2T0 = ws + H2_OFF + p0 * H2_SZ;
    float* h2T1 = ws + H2_OFF + (p0 ^ 1) * H2_SZ;

    // ================= Phase A =================
    if (t > 0) {
      // out-GEMM for step t-1: vocab row = z&3, K-half = z>>2 (h2 | context)
      const int row = z & 3, ks = z >> 2;
      float a = 0.0f;
      const float4* r0 = (const float4*)&sWo[row][ks * 128];
      const float* xp = ks ? (xT0 + 256 * BB + b) : (h2T0 + b);
      #pragma unroll 8
      for (int q = 0; q < 32; ++q) {
        float x0 = xp[0], x1 = xp[BB], x2 = xp[2 * BB], x3 = xp[3 * BB]; xp += 4 * BB;
        float4 u = r0[q];
        a += u.x * x0 + u.y * x1 + u.z * x2 + u.w * x3;
      }
      sPO[z][b] = a;
    }
    __syncthreads();
    if (t > 0 && z < 4) {
      float a = sPO[z][b] + sPO[z + 4][b] + sBo[z];
      size_t oidx = (size_t)b * (LL * VV) + (size_t)(t - 1) * VV + 4 * w + z;
      stx(out, oidx, a, isf);
    }
    if (t == LL) break;

    {
      // GEMM1: unit-local hu = z&1, K-quarter ks = z>>1 (224 of 896)
      const int hu = z & 1, ks = z >> 1;
      float a0 = 0.0f, a1 = 0.0f, a2 = 0.0f, a3 = 0.0f;
      const float4* q0 = (const float4*)&sW1[4 * hu + 0][ks * 224];
      const float4* q1 = (const float4*)&sW1[4 * hu + 1][ks * 224];
      const float4* q2 = (const float4*)&sW1[4 * hu + 2][ks * 224];
      const float4* q3 = (const float4*)&sW1[4 * hu + 3][ks * 224];
      const float* xp = xT0 + (size_t)ks * 224 * BB + b;
      #pragma unroll 4
      for (int q = 0; q < 56; ++q) {
        float x0 = xp[0], x1 = xp[BB], x2 = xp[2 * BB], x3 = xp[3 * BB]; xp += 4 * BB;
        float4 u0 = q0[q], u1 = q1[q], u2 = q2[q], u3 = q3[q];
        a0 += u0.x * x0 + u0.y * x1 + u0.z * x2 + u0.w * x3;
        a1 += u1.x * x0 + u1.y * x1 + u1.z * x2 + u1.w * x3;
        a2 += u2.x * x0 + u2.y * x1 + u2.z * x2 + u2.w * x3;
        a3 += u3.x * x0 + u3.y * x1 + u3.z * x2 + u3.w * x3;
      }
      sPA[z][0][b] = a0; sPA[z][1][b] = a1; sPA[z][2][b] = a2; sPA[z][3][b] = a3;
    }
    __syncthreads();
    if (z < 2) {
      // reduce 4 K-quarters (z' = z + 2*ks) + LSTM1; c1 owned here persistently
      float g0 = sPA[z][0][b] + sPA[z + 2][0][b] + sPA[z + 4][0][b] + sPA[z + 6][0][b] + sB1[4 * z + 0];
      float g1 = sPA[z][1][b] + sPA[z + 2][1][b] + sPA[z + 4][1][b] + sPA[z + 6][1][b] + sB1[4 * z + 1];
      float g2 = sPA[z][2][b] + sPA[z + 2][2][b] + sPA[z + 4][2][b] + sPA[z + 6][2][b] + sB1[4 * z + 2];
      float g3 = sPA[z][3][b] + sPA[z + 2][3][b] + sPA[z + 4][3][b] + sPA[z + 6][3][b] + sB1[4 * z + 3];
      float ig = sigm(g0), fg = sigm(g1), gg = tanhf(g2), og = sigm(g3);
      c1 = fg * c1 + ig * gg;
      float h1v = og * tanhf(c1);
      xT1[(size_t)(384 + 2 * w + z) * BB + b] = h1v;
    }
    grid_barrier(flags, gen, ++target);

    // ================= Phase B =================
    if (w < BB) {
      // GEMM2: gate = z&3, K-half ks = z>>2 (320 of 640 = [h1(512), h2(128)])
      const int g = z & 3, ks = z >> 2;
      float a = 0.0f;
      if (ks == 0) {
        const float4* r = (const float4*)&sW2[g][0];
        const float* xp = xT1 + 384 * BB + b;   // h1(t)[0..319]
        #pragma unroll 8
        for (int q = 0; q < 80; ++q) {
          float x0 = xp[0], x1 = xp[BB], x2 = xp[2 * BB], x3 = xp[3 * BB]; xp += 4 * BB;
          float4 u = r[q];
          a += u.x * x0 + u.y * x1 + u.z * x2 + u.w * x3;
        }
      } else {
        const float4* r = (const float4*)&sW2[g][320];
        const float* xp = xT1 + (size_t)(384 + 320) * BB + b;  // h1(t)[320..511]
        #pragma unroll 8
        for (int q = 0; q < 48; ++q) {
          float x0 = xp[0], x1 = xp[BB], x2 = xp[2 * BB], x3 = xp[3 * BB]; xp += 4 * BB;
          float4 u = r[q];
          a += u.x * x0 + u.y * x1 + u.z * x2 + u.w * x3;
        }
        const float* hp = h2T0 + b;                            // h2(t-1)
        #pragma unroll 8
        for (int q = 0; q < 32; ++q) {
          float x0 = hp[0], x1 = hp[BB], x2 = hp[2 * BB], x3 = hp[3 * BB]; hp += 4 * BB;
          float4 u = r[48 + q];
          a += u.x * x0 + u.y * x1 + u.z * x2 + u.w * x3;
        }
      }
      sPO[z][b] = a;
      __syncthreads();
      if (z == 0) {
        float gi = sPO[0][b] + sPO[4][b] + sB2[0];
        float gf = sPO[1][b] + sPO[5][b] + sB2[1];
        float gg = sPO[2][b] + sPO[6][b] + sB2[2];
        float go = sPO[3][b] + sPO[7][b] + sB2[3];
        c2 = sigm(gf) * c2 + sigm(gi) * tanhf(gg);
        float h2v = sigm(go) * tanhf(c2);
        h2T1[w * BB + b] = h2v;
      }
    } else {
      // embedding gather for step t+1 (teacher forcing: token y[:, t])
      if (tid < EE) {
        int j = w - BB;
        int tok = y[j * LL + t];
        xT1[(size_t)tid * BB + j] = ldx(emb, (size_t)tok * EE + tid, isf);
      }
    }
    grid_barrier(flags, gen, ++target);

    // ================= Phase C =================
    if (w < BB) {
      const int rb = w;
      if (tid < KVD) sH2[tid] = h2T1[tid * BB + rb];
      __syncthreads();
      const int len = enc_len[rb];
      // energy: one encoder position per thread (tid < 400)
      float e = -3.0e38f;
      if (tid < TT) {
        float acc = 0.0f;
        if (isf) {
          const float4* kr = (const float4*)((const float*)enc_key + ((size_t)rb * TT + tid) * KVD);
          #pragma unroll 8
          for (int q = 0; q < 32; ++q) {
            float4 u = kr[q];
            acc += u.x * sH2[4 * q + 0] + u.y * sH2[4 * q + 1]
                 + u.z * sH2[4 * q + 2] + u.w * sH2[4 * q + 3];
          }
        } else {
          const ushort4* kr = (const ushort4*)((const ushort_t*)enc_key + ((size_t)rb * TT + tid) * KVD);
          #pragma unroll 8
          for (int q = 0; q < 32; ++q) {
            ushort4 u = kr[q];
            acc += bf2f(u.x) * sH2[4 * q + 0] + bf2f(u.y) * sH2[4 * q + 1]
                 + bf2f(u.z) * sH2[4 * q + 2] + bf2f(u.w) * sH2[4 * q + 3];
          }
        }
        e = (tid < len) ? acc : -1e9f;
        sAttn[tid] = e;
      }
      float lmax = e;
      for (int off = 32; off > 0; off >>= 1) lmax = fmaxf(lmax, __shfl_down(lmax, off, 64));
      if ((tid & 63) == 0) sRed[tid >> 6] = lmax;
      __syncthreads();
      float m = sRed[0];
      #pragma unroll
      for (int i = 1; i < 16; ++i) m = fmaxf(m, sRed[i]);
      float lsum = 0.0f;
      if (tid < TT) { float a = expf(sAttn[tid] - m); sAttn[tid] = a; lsum = a; }
      for (int off = 32; off > 0; off >>= 1) lsum += __shfl_down(lsum, off, 64);
      __syncthreads();
      if ((tid & 63) == 0) sRed[tid >> 6] = lsum;
      __syncthreads();
      float S = 0.0f;
      #pragma unroll
      for (int i = 0; i < 16; ++i) S += sRed[i];
      const float rS = 1.0f / S;
      if (tid < TT) {
        float a = sAttn[tid] * rS;
        sAttn[tid] = a;
        if (rb == 0) stx(out, (size_t)PLOT_OFF + (size_t)t * TT + tid, a, isf);
      }
      __syncthreads();
      {
        // context: d = b, T-octile seg = z (50 positions each)
        const int seg = z, d = b;
        float acc = 0.0f;
        if (isf) {
          const float* vc = (const float*)enc_value + ((size_t)rb * TT + seg * 50) * KVD + d;
          #pragma unroll 5
          for (int tp2 = 0; tp2 < 50; ++tp2) acc += sAttn[seg * 50 + tp2] * vc[(size_t)tp2 * KVD];
        } else {
          const ushort_t* vc = (const ushort_t*)enc_value + ((size_t)rb * TT + seg * 50) * KVD + d;
          #pragma unroll 5
          for (int tp2 = 0; tp2 < 50; ++tp2) acc += sAttn[seg * 50 + tp2] * bf2f(vc[(size_t)tp2 * KVD]);
        }
        sPO[seg][d] = acc;
        __syncthreads();
        if (z == 0) {
          float ctx = sPO[0][b] + sPO[1][b] + sPO[2][b] + sPO[3][b]
                    + sPO[4][b] + sPO[5][b] + sPO[6][b] + sPO[7][b];
          xT1[(size_t)(256 + b) * BB + rb] = ctx;
        }
      }
    }
    grid_barrier(flags, gen, ++target);
  }
}

extern "C" void kernel_launch(void* const* d_in, const int* in_sizes, int n_in,
                              void* d_out, int out_size, void* d_ws, size_t ws_size,
                              hipStream_t stream) {
  const void* enc_key   = d_in[0];
  const void* enc_value = d_in[1];
  const int*  enc_len   = (const int*)d_in[2];
  const int*  y         = (const int*)d_in[3];
  const void* emb       = d_in[4];
  const void* w_ih1     = d_in[5];
  const void* w_hh1     = d_in[6];
  const void* b_ih1     = d_in[7];
  const void* b_hh1     = d_in[8];
  const void* w_ih2     = d_in[9];
  const void* w_hh2     = d_in[10];
  const void* b_ih2     = d_in[11];
  const void* b_hh2     = d_in[12];
  const void* w_out     = d_in[13];
  const void* b_out     = d_in[14];
  float* ws = (float*)d_ws;

  probe_kernel<<<dim3(1), dim3(64), 0, stream>>>(w_out, ws);
  init_kernel<<<dim3((XT_SZ + H2_SZ + NBLK + 1 + NTHR - 1) / NTHR), dim3(NTHR), 0, stream>>>(emb, ws);
  decoder_kernel<<<dim3(NBLK), dim3(DTHR), 0, stream>>>(
      enc_key, enc_value, enc_len, y, emb,
      w_ih1, w_hh1, b_ih1, b_hh1,
      w_ih2, w_hh2, b_ih2, b_hh2,
      w_out, b_out, d_out, ws);
}

// Round 3
// 31834.506 us; speedup vs baseline: 4.2357x; 4.2357x over previous
//
#include <hip/hip_runtime.h>
#include <hip/hip_bf16.h>

// Problem constants
#define BB   128   // batch
#define TT   400   // encoder length
#define KVD  128   // key/value dim (= layer2 hidden)
#define VV   1024  // vocab
#define EE   256   // embed dim
#define HH   512   // layer1 hidden
#define LL   300   // decode length
#define D1   896   // E + KV + H (layer1 input incl. recurrent)
#define NBLK 256
#define NTHR 256

// workspace layout (float units)
#define XT_SZ   (D1 * BB)             // 114688 floats per parity buffer
#define XT_OFF  0                     // 2 buffers
#define H2_SZ   (KVD * BB)            // 16384 floats per parity buffer
#define H2_OFF  (2 * XT_SZ)           // 229376
#define FLAG_OFF (H2_OFF + 2 * H2_SZ) // unsigned flags[256] + gen + isf
#define PLOT_OFF (BB * LL * VV)       // 39321600 (attn_plot offset in out)

typedef unsigned short ushort_t;

__device__ __forceinline__ float bf2f(ushort_t u) {
  return __uint_as_float(((unsigned)u) << 16);
}
__device__ __forceinline__ ushort_t f2bf(float f) {
  unsigned u = __float_as_uint(f);
  return (ushort_t)((u + 0x7FFFu + ((u >> 16) & 1u)) >> 16);  // RNE
}
__device__ __forceinline__ float sigm(float x) { return 1.0f / (1.0f + expf(-x)); }

// dtype-agnostic element load/store (isf: buffer is fp32, else bf16)
__device__ __forceinline__ float ldx(const void* p, size_t i, bool isf) {
  return isf ? ((const float*)p)[i] : bf2f(((const ushort_t*)p)[i]);
}
__device__ __forceinline__ void stx(void* p, size_t i, float v, bool isf) {
  if (isf) ((float*)p)[i] = v; else ((ushort_t*)p)[i] = f2bf(v);
}

// ---------------------------------------------------------------------------
// probe: decide whether float tensors are fp32 or bf16.
// ---------------------------------------------------------------------------
__global__ void probe_kernel(const void* __restrict__ w_out, float* __restrict__ ws) {
  if (blockIdx.x == 0 && threadIdx.x == 0) {
    const ushort_t* p = (const ushort_t*)w_out;
    int bad = 0;
    for (int i = 0; i < 512; ++i) {
      float v = bf2f(p[i]);
      if (!(fabsf(v) < 0.5f)) bad++;   // counts NaN/inf too
    }
    unsigned* flags = (unsigned*)(ws + FLAG_OFF);
    flags[NBLK + 1] = (bad > 0) ? 1u : 0u;
  }
}

// ---------------------------------------------------------------------------
// init: zero parity-0 state, seed <sos> embedding, zero barrier flags
// ---------------------------------------------------------------------------
__global__ void __launch_bounds__(NTHR) init_kernel(const void* __restrict__ emb,
                                                    float* __restrict__ ws) {
  unsigned* flags = (unsigned*)(ws + FLAG_OFF);
  const bool isf = flags[NBLK + 1] != 0;
  int idx = blockIdx.x * NTHR + threadIdx.x;
  if (idx < XT_SZ) {
    int k = idx >> 7;  // row of xT (col = idx & 127)
    ws[XT_OFF + idx] = (k < EE) ? ldx(emb, EE + k, isf) : 0.0f;  // SOS token = 1
  }
  int j = idx - XT_SZ;
  if (j >= 0 && j < H2_SZ) ws[H2_OFF + j] = 0.0f;
  int f = idx - (XT_SZ + H2_SZ);
  if (f >= 0 && f < NBLK + 1) flags[f] = 0u;   // flags[257] (isf) preserved
}

// ---------------------------------------------------------------------------
// grid barrier — cache-maintenance ONCE PER BLOCK (tid 0), not per wave.
// Entry __syncthreads drains all waves' stores to L2 (compiler emits
// s_waitcnt vmcnt(0) before s_barrier), so a single tid-0 __threadfence
// (wbl2) publishes the whole block's data before the release flag store.
// A single tid-0 __threadfence after observing gen invalidates the CU L1 +
// XCD L2 before the closing __syncthreads releases the block's waves.
// Old version executed __threadfence in every wave twice per barrier:
// 8 wbl2/inv pairs per block per barrier (32 at 1024 thr) — the prime
// suspect for the 75ms(256t) -> 150ms(1024t) scaling with flat VALU time.
// ---------------------------------------------------------------------------
__device__ __forceinline__ void grid_barrier(unsigned* flags, unsigned* gen, unsigned target) {
  __syncthreads();   // all waves' global stores drained to L2
  const int tid = threadIdx.x;
  if (blockIdx.x == 0) {
    if (tid > 0) {
      long spin = 0;
      while (__hip_atomic_load(&flags[tid], __ATOMIC_RELAXED, __HIP_MEMORY_SCOPE_AGENT) < target) {
        __builtin_amdgcn_s_sleep(2);
        if (++spin > (1L << 24)) break;  // bail-out: never expected (co-resident)
      }
    }
    __syncthreads();
    if (tid == 0) {
      __threadfence();  // release (flush block0 data) + acquire (see others' data)
      __hip_atomic_store(gen, target, __ATOMIC_RELEASE, __HIP_MEMORY_SCOPE_AGENT);
    }
    __syncthreads();
  } else {
    if (tid == 0) {
      __threadfence();  // release: publish this block's phase output
      __hip_atomic_store(&flags[blockIdx.x], target, __ATOMIC_RELEASE, __HIP_MEMORY_SCOPE_AGENT);
      long spin = 0;
      while (__hip_atomic_load(gen, __ATOMIC_RELAXED, __HIP_MEMORY_SCOPE_AGENT) < target) {
        __builtin_amdgcn_s_sleep(2);
        if (++spin > (1L << 24)) break;
      }
      __threadfence();  // acquire: invalidate stale L1/L2 before block reads
    }
    __syncthreads();
  }
}

// ---------------------------------------------------------------------------
// persistent decoder
// ---------------------------------------------------------------------------
__global__ void __launch_bounds__(NTHR) decoder_kernel(
    const void* __restrict__ enc_key,
    const void* __restrict__ enc_value,
    const int*  __restrict__ enc_len,
    const int*  __restrict__ y,
    const void* __restrict__ emb,
    const void* __restrict__ w_ih1, const void* __restrict__ w_hh1,
    const void* __restrict__ b_ih1, const void* __restrict__ b_hh1,
    const void* __restrict__ w_ih2, const void* __restrict__ w_hh2,
    const void* __restrict__ b_ih2, const void* __restrict__ b_hh2,
    const void* __restrict__ w_out, const void* __restrict__ b_out,
    void* __restrict__ out, float* __restrict__ ws)
{
  // persistent weight slices (fp32, loaded once; reads are wave-uniform broadcasts)
  __shared__ float sW1[8][D1];      // block w owns hu=2w,2w+1: rows 4h+g  (28.7 KB)
  __shared__ float sW2[4][640];     // blocks<128 own layer2 hidden w      (10.2 KB)
  __shared__ float sWo[4][256];     // block w owns vocab rows 4w..4w+3    (4 KB)
  __shared__ float sB1[8];
  __shared__ float sB2[4];
  __shared__ float sBo[4];
  __shared__ float sRed[4];
  __shared__ float sAttn[TT];
  __shared__ float sH2[KVD];
  __shared__ float sGex[2][BB];

  const int tid = threadIdx.x;
  const int w   = blockIdx.x;
  unsigned* flags = (unsigned*)(ws + FLAG_OFF);
  unsigned* gen   = flags + NBLK;
  const bool isf  = flags[NBLK + 1] != 0;   // written by probe_kernel

  // ---- one-time LDS weight staging (-> fp32) ----
  for (int i = tid; i < 8 * D1; i += NTHR) {
    int r = i / D1, k = i - r * D1;        // r = 4h+g
    int g = r & 3, h = r >> 2;
    int R = g * HH + 2 * w + h;            // global gate row in [0,2048)
    sW1[r][k] = (k < EE + KVD) ? ldx(w_ih1, (size_t)R * (EE + KVD) + k, isf)
                               : ldx(w_hh1, (size_t)R * HH + (k - (EE + KVD)), isf);
  }
  if (tid < 8) {
    int R = (tid & 3) * HH + 2 * w + (tid >> 2);
    sB1[tid] = ldx(b_ih1, R, isf) + ldx(b_hh1, R, isf);
  }
  if (w < BB) {
    for (int i = tid; i < 4 * 640; i += NTHR) {
      int g = i / 640, k = i - g * 640;
      int R = g * KVD + w;                 // global gate row in [0,512)
      sW2[g][k] = (k < HH) ? ldx(w_ih2, (size_t)R * HH + k, isf)
                           : ldx(w_hh2, (size_t)R * KVD + (k - HH), isf);
    }
    if (tid < 4) {
      int R = tid * KVD + w;
      sB2[tid] = ldx(b_ih2, R, isf) + ldx(b_hh2, R, isf);
    }
  }
  for (int i = tid; i < 4 * 256; i += NTHR) {
    int r = i >> 8, d = i & 255;
    sWo[r][d] = ldx(w_out, (size_t)(4 * w + r) * 256 + d, isf);
  }
  if (tid < 4) sBo[tid] = ldx(b_out, 4 * w + tid, isf);
  __syncthreads();

  const int b  = tid & 127;   // batch column
  const int hi = tid >> 7;    // half: 0/1
  float c1 = 0.0f;            // c1[hu=2w+hi][b] lives here across all steps
  float c2 = 0.0f;            // (w<128, hi==0): c2[w][b]

  unsigned target = 0;

  for (int t = 0; t <= LL; ++t) {
    const int p0 = t & 1;
    float* xT0  = ws + XT_OFF + p0 * XT_SZ;
    float* xT1  = ws + XT_OFF + (p0 ^ 1) * XT_SZ;
    float* h2T0 = ws + H2_OFF + p0 * H2_SZ;
    float* h2T1 = ws + H2_OFF + (p0 ^ 1) * H2_SZ;

    // ================= Phase A =================
    if (t > 0) {
      // output GEMM for step t-1: logits = [h2, context] @ w_out^T + b_out
      float a0 = sBo[2 * hi], a1 = sBo[2 * hi + 1];
      const float4* r0 = (const float4*)&sWo[2 * hi][0];
      const float4* r1 = (const float4*)&sWo[2 * hi + 1][0];
      const float* hp = h2T0 + b;
      #pragma unroll 4
      for (int q = 0; q < 32; ++q) {
        float x0 = hp[0], x1 = hp[BB], x2 = hp[2 * BB], x3 = hp[3 * BB]; hp += 4 * BB;
        float4 u0 = r0[q], u1 = r1[q];
        a0 += u0.x * x0 + u0.y * x1 + u0.z * x2 + u0.w * x3;
        a1 += u1.x * x0 + u1.y * x1 + u1.z * x2 + u1.w * x3;
      }
      const float* cp = xT0 + 256 * BB + b;
      #pragma unroll 4
      for (int q = 0; q < 32; ++q) {
        float x0 = cp[0], x1 = cp[BB], x2 = cp[2 * BB], x3 = cp[3 * BB]; cp += 4 * BB;
        float4 u0 = r0[32 + q], u1 = r1[32 + q];
        a0 += u0.x * x0 + u0.y * x1 + u0.z * x2 + u0.w * x3;
        a1 += u1.x * x0 + u1.y * x1 + u1.z * x2 + u1.w * x3;
      }
      int v = 4 * w + 2 * hi;
      size_t oidx = (size_t)b * (LL * VV) + (size_t)(t - 1) * VV + v;
      stx(out, oidx, a0, isf);
      stx(out, oidx + 1, a1, isf);
    }
    if (t == LL) break;                                   // final epilogue done

    {
      // GEMM1 + LSTM1 for step t: x = [emb_t, context, h1] (rows of xT0)
      const int hu = 2 * w + hi;
      float a0 = sB1[4 * hi + 0], a1 = sB1[4 * hi + 1];
      float a2 = sB1[4 * hi + 2], a3 = sB1[4 * hi + 3];
      const float4* q0 = (const float4*)&sW1[4 * hi + 0][0];
      const float4* q1 = (const float4*)&sW1[4 * hi + 1][0];
      const float4* q2 = (const float4*)&sW1[4 * hi + 2][0];
      const float4* q3 = (const float4*)&sW1[4 * hi + 3][0];
      const float* xp = xT0 + b;
      #pragma unroll 2
      for (int q = 0; q < 224; ++q) {
        float x0 = xp[0], x1 = xp[BB], x2 = xp[2 * BB], x3 = xp[3 * BB]; xp += 4 * BB;
        float4 u0 = q0[q], u1 = q1[q], u2 = q2[q], u3 = q3[q];
        a0 += u0.x * x0 + u0.y * x1 + u0.z * x2 + u0.w * x3;
        a1 += u1.x * x0 + u1.y * x1 + u1.z * x2 + u1.w * x3;
        a2 += u2.x * x0 + u2.y * x1 + u2.z * x2 + u2.w * x3;
        a3 += u3.x * x0 + u3.y * x1 + u3.z * x2 + u3.w * x3;
      }
      float ig = sigm(a0), fg = sigm(a1), gg = tanhf(a2), og = sigm(a3);
      c1 = fg * c1 + ig * gg;
      float h1v = og * tanhf(c1);
      xT1[(384 + hu) * BB + b] = h1v;
    }
    grid_barrier(flags, gen, ++target);

    // ================= Phase B =================
    if (w < BB) {
      // GEMM2 + LSTM2: gates2 = [h1, h2] @ W2^T ; this block owns hidden unit w
      float a0 = sB2[2 * hi], a1 = sB2[2 * hi + 1];
      const float4* r0 = (const float4*)&sW2[2 * hi][0];
      const float4* r1 = (const float4*)&sW2[2 * hi + 1][0];
      const float* xp = xT1 + 384 * BB + b;   // h1(t)
      #pragma unroll 4
      for (int q = 0; q < 128; ++q) {
        float x0 = xp[0], x1 = xp[BB], x2 = xp[2 * BB], x3 = xp[3 * BB]; xp += 4 * BB;
        float4 u0 = r0[q], u1 = r1[q];
        a0 += u0.x * x0 + u0.y * x1 + u0.z * x2 + u0.w * x3;
        a1 += u1.x * x0 + u1.y * x1 + u1.z * x2 + u1.w * x3;
      }
      const float* hp = h2T0 + b;             // h2(t-1)
      #pragma unroll 4
      for (int q = 0; q < 32; ++q) {
        float x0 = hp[0], x1 = hp[BB], x2 = hp[2 * BB], x3 = hp[3 * BB]; hp += 4 * BB;
        float4 u0 = r0[128 + q], u1 = r1[128 + q];
        a0 += u0.x * x0 + u0.y * x1 + u0.z * x2 + u0.w * x3;
        a1 += u1.x * x0 + u1.y * x1 + u1.z * x2 + u1.w * x3;
      }
      if (hi == 1) { sGex[0][b] = tanhf(a0); sGex[1][b] = sigm(a1); }  // g, o
      __syncthreads();
      if (hi == 0) {                                                   // i, f
        c2 = sigm(a1) * c2 + sigm(a0) * sGex[0][b];
        float h2v = sGex[1][b] * tanhf(c2);
        h2T1[w * BB + b] = h2v;
      }
    } else {
      // embedding gather for step t+1 (teacher forcing: token y[:, t])
      int j = w - BB;
      int tok = y[j * LL + t];
      xT1[tid * BB + j] = ldx(emb, (size_t)tok * EE + tid, isf);  // tid in [0,256)=E
    }
    grid_barrier(flags, gen, ++target);

    // ================= Phase C =================
    if (w < BB) {
      const int rb = w;                                  // batch row pinned to block
      if (tid < KVD) sH2[tid] = h2T1[tid * BB + rb];
      __syncthreads();
      const int len = enc_len[rb];
      float lmax = -3.0e38f;
      #pragma unroll
      for (int rep = 0; rep < 2; ++rep) {
        int tp = tid + rep * 256;
        float e = -3.0e38f;
        if (tp < TT) {
          float acc = 0.0f;
          if (isf) {
            const float4* kr = (const float4*)((const float*)enc_key + ((size_t)rb * TT + tp) * KVD);
            #pragma unroll 8
            for (int q = 0; q < 32; ++q) {
              float4 u = kr[q];
              acc += u.x * sH2[4 * q + 0] + u.y * sH2[4 * q + 1]
                   + u.z * sH2[4 * q + 2] + u.w * sH2[4 * q + 3];
            }
          } else {
            const ushort4* kr = (const ushort4*)((const ushort_t*)enc_key + ((size_t)rb * TT + tp) * KVD);
            #pragma unroll 8
            for (int q = 0; q < 32; ++q) {
              ushort4 u = kr[q];
              acc += bf2f(u.x) * sH2[4 * q + 0] + bf2f(u.y) * sH2[4 * q + 1]
                   + bf2f(u.z) * sH2[4 * q + 2] + bf2f(u.w) * sH2[4 * q + 3];
            }
          }
          e = (tp < len) ? acc : -1e9f;
          sAttn[tp] = e;
        }
        lmax = fmaxf(lmax, e);
      }
      for (int off = 32; off > 0; off >>= 1) lmax = fmaxf(lmax, __shfl_down(lmax, off, 64));
      if ((tid & 63) == 0) sRed[tid >> 6] = lmax;
      __syncthreads();
      const float m = fmaxf(fmaxf(sRed[0], sRed[1]), fmaxf(sRed[2], sRed[3]));
      float lsum = 0.0f;
      #pragma unroll
      for (int rep = 0; rep < 2; ++rep) {
        int tp = tid + rep * 256;
        if (tp < TT) { float a = expf(sAttn[tp] - m); sAttn[tp] = a; lsum += a; }
      }
      for (int off = 32; off > 0; off >>= 1) lsum += __shfl_down(lsum, off, 64);
      __syncthreads();
      if ((tid & 63) == 0) sRed[tid >> 6] = lsum;
      __syncthreads();
      const float rS = 1.0f / (sRed[0] + sRed[1] + sRed[2] + sRed[3]);
      #pragma unroll
      for (int rep = 0; rep < 2; ++rep) {
        int tp = tid + rep * 256;
        if (tp < TT) {
          float a = sAttn[tp] * rS;
          sAttn[tp] = a;
          if (rb == 0) stx(out, (size_t)PLOT_OFF + (size_t)t * TT + tp, a, isf);  // attn_plot
        }
      }
      __syncthreads();
      {
        // context = attn @ enc_value ; threads split T into two halves
        const int d = tid & 127, half = tid >> 7;
        float acc = 0.0f;
        if (isf) {
          const float* vc = (const float*)enc_value + ((size_t)rb * TT + half * 200) * KVD + d;
          for (int tp2 = 0; tp2 < 200; ++tp2) acc += sAttn[half * 200 + tp2] * vc[(size_t)tp2 * KVD];
        } else {
          const ushort_t* vc = (const ushort_t*)enc_value + ((size_t)rb * TT + half * 200) * KVD + d;
          for (int tp2 = 0; tp2 < 200; ++tp2) acc += sAttn[half * 200 + tp2] * bf2f(vc[(size_t)tp2 * KVD]);
        }
        if (half == 1) sGex[0][d] = acc;
        __syncthreads();
        if (half == 0) xT1[(256 + d) * BB + rb] = acc + sGex[0][d];
      }
    }
    grid_barrier(flags, gen, ++target);
  }
}

extern "C" void kernel_launch(void* const* d_in, const int* in_sizes, int n_in,
                              void* d_out, int out_size, void* d_ws, size_t ws_size,
                              hipStream_t stream) {
  const void* enc_key   = d_in[0];
  const void* enc_value = d_in[1];
  const int*  enc_len   = (const int*)d_in[2];
  const int*  y         = (const int*)d_in[3];
  const void* emb       = d_in[4];
  const void* w_ih1     = d_in[5];
  const void* w_hh1     = d_in[6];
  const void* b_ih1     = d_in[7];
  const void* b_hh1     = d_in[8];
  const void* w_ih2     = d_in[9];
  const void* w_hh2     = d_in[10];
  const void* b_ih2     = d_in[11];
  const void* b_hh2     = d_in[12];
  const void* w_out     = d_in[13];
  const void* b_out     = d_in[14];
  float* ws = (float*)d_ws;

  // 1) detect fp32 vs bf16 (writes isf flag into ws)
  probe_kernel<<<dim3(1), dim3(64), 0, stream>>>(w_out, ws);
  // 2) zero state/barrier region, seed <sos> embedding (reads isf)
  init_kernel<<<dim3((XT_SZ + H2_SZ + NBLK + 1 + NTHR - 1) / NTHR), dim3(NTHR), 0, stream>>>(emb, ws);
  // 3) persistent decode
  decoder_kernel<<<dim3(NBLK), dim3(NTHR), 0, stream>>>(
      enc_key, enc_value, enc_len, y, emb,
      w_ih1, w_hh1, b_ih1, b_hh1,
      w_ih2, w_hh2, b_ih2, b_hh2,
      w_out, b_out, d_out, ws);
}